// Round 1
// baseline (427.415 us; speedup 1.0000x reference)
//
#include <hip/hip_runtime.h>

#define NB 4
#define NN 2048
#define ND 512
#define NE 16
#define NH 1024
#define CAP 256
#define NTOK (NB*NN)

// ---------------- linear1: h = X @ W1 + b1  (M=8192, K=512, N=512) ----------------
__global__ __launch_bounds__(256) void linear1_kernel(const float* __restrict__ X,
                                                      const float* __restrict__ W1,
                                                      const float* __restrict__ b1,
                                                      float* __restrict__ h) {
    __shared__ __align__(16) float As[16][68];   // padded, transposed: As[k][m]
    __shared__ __align__(16) float Bs[16][64];
    const int tid = threadIdx.x;
    const int tx = tid & 15, ty = tid >> 4;
    const int m0 = blockIdx.y * 64, n0 = blockIdx.x * 64;
    float acc[4][4] = {};
    for (int k0 = 0; k0 < ND; k0 += 16) {
        #pragma unroll
        for (int i = 0; i < 4; ++i) {
            int e = tid + 256 * i;           // 0..1023
            int r = e >> 4, kk = e & 15;
            As[kk][r] = X[(size_t)(m0 + r) * ND + k0 + kk];
        }
        #pragma unroll
        for (int i = 0; i < 4; ++i) {
            int e = tid + 256 * i;
            int r = e >> 6, c = e & 63;
            Bs[r][c] = W1[(size_t)(k0 + r) * ND + n0 + c];
        }
        __syncthreads();
        #pragma unroll
        for (int k = 0; k < 16; ++k) {
            const float4 a4 = *(const float4*)(&As[k][4 * ty]);
            const float4 b4 = *(const float4*)(&Bs[k][4 * tx]);
            const float av[4] = {a4.x, a4.y, a4.z, a4.w};
            const float bv[4] = {b4.x, b4.y, b4.z, b4.w};
            #pragma unroll
            for (int i = 0; i < 4; ++i)
                #pragma unroll
                for (int j = 0; j < 4; ++j)
                    acc[i][j] = fmaf(av[i], bv[j], acc[i][j]);
        }
        __syncthreads();
    }
    #pragma unroll
    for (int i = 0; i < 4; ++i) {
        int m = m0 + 4 * ty + i;
        #pragma unroll
        for (int j = 0; j < 4; ++j) {
            int n = n0 + 4 * tx + j;
            h[(size_t)m * ND + n] = acc[i][j] + b1[n];
        }
    }
}

// ---------------- v = W3 @ W4 ; c0 = b3@W4 + b4 ----------------
__global__ void v_kernel(const float* __restrict__ W3, const float* __restrict__ b3,
                         const float* __restrict__ W4, const float* __restrict__ b4,
                         float* __restrict__ vv, float* __restrict__ c0) {
    int d = blockIdx.x * 256 + threadIdx.x;
    if (d < ND) {
        float s = 0.f;
        #pragma unroll
        for (int j = 0; j < 4; ++j) s += W3[d * 4 + j] * W4[j];
        vv[d] = s;
    }
    if (d == 0) {
        float s = 0.f;
        #pragma unroll
        for (int j = 0; j < 4; ++j) s += b3[j] * W4[j];
        *c0 = s + b4[0];
    }
}

// ---------------- u[e][h] = We2[e][h][:] . v ----------------
__global__ __launch_bounds__(256) void u_kernel(const float* __restrict__ We2,
                                                const float* __restrict__ vv,
                                                float* __restrict__ u) {
    const int bid = blockIdx.x;             // E * (H/16) = 1024
    const int e = bid >> 6, rb = bid & 63;
    const int tid = threadIdx.x;
    const int rl = tid >> 4, dl = tid & 15;
    const int hrow = rb * 16 + rl;
    const float* wrow = We2 + ((size_t)e * NH + hrow) * ND;
    float sum = 0.f;
    for (int j = 0; j < 32; ++j) sum += wrow[dl + 16 * j] * vv[dl + 16 * j];
    #pragma unroll
    for (int off = 8; off >= 1; off >>= 1) sum += __shfl_down(sum, off, 16);
    if (dl == 0) u[e * NH + hrow] = sum;
}

// ---------------- gating: one wave per token ----------------
__global__ __launch_bounds__(256) void gating_kernel(const float* __restrict__ h,
                                                     const float* __restrict__ Wg,
                                                     const float* __restrict__ probs,
                                                     int* __restrict__ idx1a, int* __restrict__ idx2a,
                                                     float* __restrict__ g1a, float* __restrict__ g2a,
                                                     int* __restrict__ pos1a, int* __restrict__ pos2a) {
    __shared__ float WgT[NE * ND];          // 32KB, WgT[e*512+d]
    const int tid = threadIdx.x;
    for (int i = 0; i < 32; ++i) {
        int el = tid + 256 * i;             // 8192
        int d = el >> 4, e = el & 15;
        WgT[e * ND + d] = Wg[el];
    }
    __syncthreads();
    const int w = tid >> 6, l = tid & 63;
    const int tok = blockIdx.x * 4 + w;
    const float* hrow = h + (size_t)tok * ND;
    float acc[NE] = {};
    for (int j = 0; j < 8; ++j) {
        float hv = hrow[64 * j + l];
        #pragma unroll
        for (int e = 0; e < NE; ++e) acc[e] += hv * WgT[e * ND + 64 * j + l];
    }
    #pragma unroll
    for (int off = 32; off >= 1; off >>= 1)
        #pragma unroll
        for (int e = 0; e < NE; ++e) acc[e] += __shfl_xor(acc[e], off);

    if (l == 0) {
        float m = acc[0];
        #pragma unroll
        for (int e = 1; e < NE; ++e) m = fmaxf(m, acc[e]);
        float raw[NE]; float s = 0.f;
        #pragma unroll
        for (int e = 0; e < NE; ++e) { raw[e] = expf(acc[e] - m); s += raw[e]; }
        #pragma unroll
        for (int e = 0; e < NE; ++e) raw[e] = raw[e] / s;
        // top1 (first max)
        int i1 = 0; float g1 = raw[0];
        #pragma unroll
        for (int e = 1; e < NE; ++e) if (raw[e] > g1) { g1 = raw[e]; i1 = e; }
        // top2 (first max excluding i1)
        int i2 = -1; float g2 = -1.f;
        #pragma unroll
        for (int e = 0; e < NE; ++e) if (e != i1 && raw[e] > g2) { g2 = raw[e]; i2 = e; }
        float denom = g1 + g2 + 1e-9f;
        float g1n = g1 / denom, g2n = g2 / denom;
        bool flag = probs[tok] < (g2n / 0.2f);
        idx1a[tok] = i1;
        idx2a[tok] = flag ? i2 : -1;
        g1a[tok] = g1n;
        g2a[tok] = g2n;
        pos1a[tok] = -1;
        pos2a[tok] = -1;
    }
}

// ---------------- scan: one wave per (b,e), ballot prefix cumsum ----------------
__global__ __launch_bounds__(64) void scan_kernel(const int* __restrict__ idx1a,
                                                  const int* __restrict__ idx2a,
                                                  int* __restrict__ pos1a, int* __restrict__ pos2a,
                                                  int* __restrict__ slot_token) {
    const int bb = blockIdx.x;              // 64
    const int b = bb >> 4, e = bb & 15;
    const int l = threadIdx.x;
    int* slot = slot_token + (e * NB + b) * CAP;
    const unsigned long long below = (l == 0) ? 0ull : ((1ull << l) - 1ull);
    int c = 0;
    for (int base = 0; base < NN; base += 64) {
        int n = base + l;
        bool p = (idx1a[b * NN + n] == e);
        unsigned long long m = __ballot(p);
        int pre = __popcll(m & below);
        if (p) {
            int pos = c + pre;
            if (pos < CAP) { slot[pos] = n; pos1a[b * NN + n] = pos; }
        }
        c += __popcll(m);
    }
    int c2 = (c < CAP) ? c : CAP;
    for (int base = 0; base < NN; base += 64) {
        int n = base + l;
        bool p = (idx2a[b * NN + n] == e);
        unsigned long long m = __ballot(p);
        int pre = __popcll(m & below);
        if (p) {
            int pos = c2 + pre;
            if (pos < CAP) { slot[pos] = n; pos2a[b * NN + n] = pos; }
        }
        c2 += __popcll(m);
    }
    int nfill = (c2 < CAP) ? c2 : CAP;
    for (int i = nfill + l; i < CAP; i += 64) slot[i] = -1;
}

// ---------------- expert: per block 16 slots x full H, fused lrelu . u ----------------
__global__ __launch_bounds__(256) void expert_kernel(const float* __restrict__ h,
                                                     const float* __restrict__ We1,
                                                     const float* __restrict__ u,
                                                     const int* __restrict__ slot_token,
                                                     float* __restrict__ s_slot) {
    __shared__ __align__(16) float hT[ND][16];   // 32KB, hT[d][slot]
    __shared__ __align__(16) float wt[16][256];  // 16KB
    __shared__ int toks[16];
    const int e = blockIdx.z, b = blockIdx.y, c0 = blockIdx.x * 16;
    const int tid = threadIdx.x;
    if (tid < 16) toks[tid] = slot_token[(e * NB + b) * CAP + c0 + tid];
    __syncthreads();
    for (int i = 0; i < 32; ++i) {
        int el = tid + 256 * i;             // 8192 = 16*512
        int s = el >> 9, d = el & 511;
        int n = toks[s];
        hT[d][s] = (n >= 0) ? h[((size_t)b * NN + n) * ND + d] : 0.0f;
    }
    const int sg = tid >> 6;   // wave id 0..3 -> slot group
    const int hg = tid & 63;   // lane -> h group
    float sacc[4] = {0.f, 0.f, 0.f, 0.f};
    for (int hc = 0; hc < 4; ++hc) {
        float acc[4][4] = {};
        for (int kt = 0; kt < ND; kt += 16) {
            __syncthreads();
            #pragma unroll
            for (int i = 0; i < 16; ++i) {
                int el = tid + 256 * i;     // 4096 = 16*256
                int r = el >> 8, col = el & 255;
                wt[r][col] = We1[((size_t)e * ND + kt + r) * NH + hc * 256 + col];
            }
            __syncthreads();
            #pragma unroll
            for (int k = 0; k < 16; ++k) {
                const float4 a4 = *(const float4*)(&hT[kt + k][4 * sg]);   // wave-uniform -> broadcast
                const float4 b4 = *(const float4*)(&wt[k][4 * hg]);
                const float av[4] = {a4.x, a4.y, a4.z, a4.w};
                const float bv[4] = {b4.x, b4.y, b4.z, b4.w};
                #pragma unroll
                for (int i = 0; i < 4; ++i)
                    #pragma unroll
                    for (int j = 0; j < 4; ++j)
                        acc[i][j] = fmaf(av[i], bv[j], acc[i][j]);
            }
        }
        const float4 uv = *(const float4*)(&u[e * NH + hc * 256 + 4 * hg]);
        const float uvv[4] = {uv.x, uv.y, uv.z, uv.w};
        #pragma unroll
        for (int si = 0; si < 4; ++si) {
            float p = 0.f;
            #pragma unroll
            for (int j = 0; j < 4; ++j) {
                float x = acc[si][j];
                x = (x > 0.f) ? x : 0.01f * x;
                p += x * uvv[j];
            }
            sacc[si] += p;
        }
    }
    #pragma unroll
    for (int off = 32; off >= 1; off >>= 1)
        #pragma unroll
        for (int si = 0; si < 4; ++si) sacc[si] += __shfl_down(sacc[si], off);
    if (hg == 0) {
        #pragma unroll
        for (int si = 0; si < 4; ++si)
            s_slot[(e * NB + b) * CAP + c0 + 4 * sg + si] = sacc[si];
    }
}

// ---------------- final: per token combine + collapsed output projection ----------------
__global__ __launch_bounds__(256) void final_kernel(const int* __restrict__ idx1a, const int* __restrict__ idx2a,
                                                    const int* __restrict__ pos1a, const int* __restrict__ pos2a,
                                                    const float* __restrict__ g1a, const float* __restrict__ g2a,
                                                    const float* __restrict__ s_slot, const float* __restrict__ c0,
                                                    float* __restrict__ out) {
    int tok = blockIdx.x * 256 + threadIdx.x;   // 8192
    int b = tok >> 11;
    float s = *c0;
    int p1 = pos1a[tok];
    if (p1 >= 0) s += g1a[tok] * s_slot[(idx1a[tok] * NB + b) * CAP + p1];
    int p2 = pos2a[tok];
    if (p2 >= 0) s += g2a[tok] * s_slot[(idx2a[tok] * NB + b) * CAP + p2];
    out[tok] = s;
}

extern "C" void kernel_launch(void* const* d_in, const int* in_sizes, int n_in,
                              void* d_out, int out_size, void* d_ws, size_t ws_size,
                              hipStream_t stream) {
    const float* X    = (const float*)d_in[0];
    const float* probs= (const float*)d_in[1];
    const float* W1   = (const float*)d_in[2];
    const float* b1   = (const float*)d_in[3];
    const float* Wg   = (const float*)d_in[4];
    const float* We1  = (const float*)d_in[5];
    const float* We2  = (const float*)d_in[6];
    const float* W3   = (const float*)d_in[7];
    const float* b3   = (const float*)d_in[8];
    const float* W4   = (const float*)d_in[9];
    const float* b4   = (const float*)d_in[10];
    float* out = (float*)d_out;

    char* ws = (char*)d_ws;
    size_t off = 0;
    auto alloc = [&](size_t bytes) { void* p = ws + off; off += (bytes + 255) & ~(size_t)255; return p; };
    float* h       = (float*)alloc((size_t)NTOK * ND * 4);       // 16 MB
    float* vv      = (float*)alloc(ND * 4);
    float* c0      = (float*)alloc(256);
    float* u       = (float*)alloc(NE * NH * 4);
    int*   idx1a   = (int*)alloc(NTOK * 4);
    int*   idx2a   = (int*)alloc(NTOK * 4);
    int*   pos1a   = (int*)alloc(NTOK * 4);
    int*   pos2a   = (int*)alloc(NTOK * 4);
    float* g1a     = (float*)alloc(NTOK * 4);
    float* g2a     = (float*)alloc(NTOK * 4);
    int*   slot_tok= (int*)alloc(NE * NB * CAP * 4);
    float* s_slot  = (float*)alloc(NE * NB * CAP * 4);
    (void)ws_size; (void)in_sizes; (void)n_in; (void)out_size;

    linear1_kernel<<<dim3(ND / 64, NTOK / 64), 256, 0, stream>>>(X, W1, b1, h);
    v_kernel<<<2, 256, 0, stream>>>(W3, b3, W4, b4, vv, c0);
    u_kernel<<<NE * (NH / 16), 256, 0, stream>>>(We2, vv, u);
    gating_kernel<<<NTOK / 4, 256, 0, stream>>>(h, Wg, probs, idx1a, idx2a, g1a, g2a, pos1a, pos2a);
    scan_kernel<<<NB * NE, 64, 0, stream>>>(idx1a, idx2a, pos1a, pos2a, slot_tok);
    expert_kernel<<<dim3(CAP / 16, NB, NE), 256, 0, stream>>>(h, We1, u, slot_tok, s_slot);
    final_kernel<<<NTOK / 256, 256, 0, stream>>>(idx1a, idx2a, pos1a, pos2a, g1a, g2a, s_slot, c0, out);
}

// Round 2
// 138.920 us; speedup vs baseline: 3.0767x; 3.0767x over previous
//
#include <hip/hip_runtime.h>
#include <hip/hip_bf16.h>

#define NB 4
#define NN 2048
#define ND 512
#define NE 16
#define NH 1024
#define CAP 256
#define NTOK (NB*NN)

typedef __attribute__((ext_vector_type(8))) short bf16x8;
typedef __attribute__((ext_vector_type(4))) float f32x4;

__device__ __forceinline__ void gload16(const void* gsrc, void* lds) {
    __builtin_amdgcn_global_load_lds((const __attribute__((address_space(1))) void*)gsrc,
                                     (__attribute__((address_space(3))) void*)lds, 16, 0, 0);
}
__device__ __forceinline__ unsigned short f2bf(float f) {
    union { __hip_bfloat16 b; unsigned short u; } v; v.b = __float2bfloat16(f); return v.u;
}

// ---------------- X -> bf16, and zero the OOB source buffer ----------------
__global__ __launch_bounds__(256) void convert_x_kernel(const float* __restrict__ X,
                                                        unsigned short* __restrict__ Xbf,
                                                        float* __restrict__ zbuf) {
    int i = (blockIdx.x * 256 + threadIdx.x) * 4;
    float4 v = *(const float4*)(X + i);
    ushort4 o; o.x = f2bf(v.x); o.y = f2bf(v.y); o.z = f2bf(v.z); o.w = f2bf(v.w);
    *(ushort4*)(Xbf + i) = o;
    if (blockIdx.x == 0) zbuf[threadIdx.x] = 0.f;
}

// ---------------- tiled f32 [R][C] -> bf16 [C][R] transpose (batched) ----------------
__global__ __launch_bounds__(256) void transpose_bf16_kernel(const float* __restrict__ src,
                                                             unsigned short* __restrict__ dst,
                                                             int R, int C) {
    __shared__ float t[32][33];
    const size_t zoff = (size_t)blockIdx.z * R * C;
    int r0 = blockIdx.y * 32, c0 = blockIdx.x * 32;
    #pragma unroll
    for (int i = 0; i < 4; ++i) {
        int idx = threadIdx.x + 256 * i;
        int lr = idx >> 5, lc = idx & 31;
        t[lr][lc] = src[zoff + (size_t)(r0 + lr) * C + (c0 + lc)];
    }
    __syncthreads();
    #pragma unroll
    for (int i = 0; i < 4; ++i) {
        int idx = threadIdx.x + 256 * i;
        int lr = idx >> 5, lc = idx & 31;
        dst[zoff + (size_t)(c0 + lr) * R + (r0 + lc)] = f2bf(t[lc][lr]);
    }
}

// ---------------- WcT[e][d] = sum_j W1[d][j] Wg[j][e]  (gating stays f32) ----------------
__global__ __launch_bounds__(256) void wc_kernel(const float* __restrict__ W1,
                                                 const float* __restrict__ Wg,
                                                 float* __restrict__ WcT) {
    int d = blockIdx.x * 16 + (threadIdx.x >> 4);
    int e = threadIdx.x & 15;
    float s = 0.f;
    for (int j = 0; j < ND; ++j) s = fmaf(W1[d * ND + j], Wg[j * NE + e], s);
    WcT[e * ND + d] = s;
}

// ---------------- v = W3 @ W4 ; c0 = b3@W4 + b4 ----------------
__global__ void v_kernel(const float* __restrict__ W3, const float* __restrict__ b3,
                         const float* __restrict__ W4, const float* __restrict__ b4,
                         float* __restrict__ vv, float* __restrict__ c0) {
    int d = blockIdx.x * 256 + threadIdx.x;
    if (d < ND) {
        float s = 0.f;
        #pragma unroll
        for (int j = 0; j < 4; ++j) s += W3[d * 4 + j] * W4[j];
        vv[d] = s;
    }
    if (d == 0) {
        float s = 0.f;
        #pragma unroll
        for (int j = 0; j < 4; ++j) s += b3[j] * W4[j];
        *c0 = s + b4[0];
    }
}

// ---------------- u[e][h] = We2[e][h][:] . v ----------------
__global__ __launch_bounds__(256) void u_kernel(const float* __restrict__ We2,
                                                const float* __restrict__ vv,
                                                float* __restrict__ u) {
    const int bid = blockIdx.x;             // E * (H/16) = 1024
    const int e = bid >> 6, rb = bid & 63;
    const int tid = threadIdx.x;
    const int rl = tid >> 4, dl = tid & 15;
    const int hrow = rb * 16 + rl;
    const float* wrow = We2 + ((size_t)e * NH + hrow) * ND;
    float sum = 0.f;
    for (int j = 0; j < 32; ++j) sum += wrow[dl + 16 * j] * vv[dl + 16 * j];
    #pragma unroll
    for (int off = 8; off >= 1; off >>= 1) sum += __shfl_down(sum, off, 16);
    if (dl == 0) u[e * NH + hrow] = sum;
}

// ---------------- linear1 MFMA: hbf = bf16( Xbf @ W1 + b1 ) ----------------
__global__ __launch_bounds__(512) void linear1_mfma_kernel(const unsigned short* __restrict__ Xbf,
                                                           const unsigned short* __restrict__ W1T,
                                                           const float* __restrict__ b1,
                                                           unsigned short* __restrict__ hbf) {
    __shared__ char Ash[2][16384];
    __shared__ char Bsh[2][16384];
    const int tid = threadIdx.x;
    const int w = tid >> 6, l = tid & 63;
    const int wm = w >> 1, wn = w & 1;      // 4 x 2 wave grid, wave tile 32x64
    const int lr = l & 15, lk = l >> 4;
    const int m0 = blockIdx.y * 128, n0 = blockIdx.x * 128;

    auto stage = [&](int Ks, int buf) {
        #pragma unroll
        for (int i = 0; i < 2; ++i) {
            int o = i * 8192 + tid * 16;
            int r = o >> 7, bb = o & 127;
            int sb = bb ^ ((r & 7) << 4);
            gload16((const char*)Xbf + ((size_t)(m0 + r) * ND + Ks * 64) * 2 + sb,
                    Ash[buf] + i * 8192 + w * 1024);
            gload16((const char*)W1T + ((size_t)(n0 + r) * ND + Ks * 64) * 2 + sb,
                    Bsh[buf] + i * 8192 + w * 1024);
        }
    };

    f32x4 acc[2][4] = {};
    stage(0, 0);
    __syncthreads();
    for (int Ks = 0; Ks < 8; ++Ks) {
        int buf = Ks & 1;
        if (Ks < 7) stage(Ks + 1, buf ^ 1);
        #pragma unroll
        for (int k32 = 0; k32 < 2; ++k32) {
            int kb = (k32 * 32 + 8 * lk) * 2;
            bf16x8 a[2], bfr[4];
            #pragma unroll
            for (int mi = 0; mi < 2; ++mi) {
                int row = wm * 32 + mi * 16 + lr;
                a[mi] = *(const bf16x8*)(Ash[buf] + row * 128 + (kb ^ ((row & 7) << 4)));
            }
            #pragma unroll
            for (int ni = 0; ni < 4; ++ni) {
                int row = wn * 64 + ni * 16 + lr;
                bfr[ni] = *(const bf16x8*)(Bsh[buf] + row * 128 + (kb ^ ((row & 7) << 4)));
            }
            #pragma unroll
            for (int mi = 0; mi < 2; ++mi)
                #pragma unroll
                for (int ni = 0; ni < 4; ++ni)
                    acc[mi][ni] = __builtin_amdgcn_mfma_f32_16x16x32_bf16(a[mi], bfr[ni], acc[mi][ni], 0, 0, 0);
        }
        __syncthreads();
    }
    #pragma unroll
    for (int mi = 0; mi < 2; ++mi)
        #pragma unroll
        for (int ni = 0; ni < 4; ++ni) {
            int col = n0 + wn * 64 + ni * 16 + lr;
            float bb1 = b1[col];
            #pragma unroll
            for (int r = 0; r < 4; ++r) {
                int m = m0 + wm * 32 + mi * 16 + lk * 4 + r;
                hbf[(size_t)m * ND + col] = f2bf(acc[mi][ni][r] + bb1);
            }
        }
}

// ---------------- gating from X and WcT (f32, matches reference numerics) ----------------
__global__ __launch_bounds__(256) void gating_kernel(const float* __restrict__ X,
                                                     const float* __restrict__ WcT,
                                                     const float* __restrict__ probs,
                                                     int* __restrict__ idx1a, int* __restrict__ idx2a,
                                                     float* __restrict__ g1a, float* __restrict__ g2a,
                                                     int* __restrict__ pos1a, int* __restrict__ pos2a) {
    __shared__ float wc[NE * ND];           // 32KB
    const int tid = threadIdx.x;
    #pragma unroll
    for (int i = 0; i < 32; ++i) wc[tid + 256 * i] = WcT[tid + 256 * i];
    __syncthreads();
    const int w = tid >> 6, l = tid & 63;
    for (int j = 0; j < 4; ++j) {
        int tok = blockIdx.x * 16 + 4 * j + w;
        const float* xrow = X + (size_t)tok * ND;
        float acc[NE] = {};
        for (int jj = 0; jj < 8; ++jj) {
            float xv = xrow[64 * jj + l];
            #pragma unroll
            for (int e = 0; e < NE; ++e) acc[e] = fmaf(xv, wc[e * ND + 64 * jj + l], acc[e]);
        }
        #pragma unroll
        for (int off = 32; off >= 1; off >>= 1)
            #pragma unroll
            for (int e = 0; e < NE; ++e) acc[e] += __shfl_xor(acc[e], off);

        if (l == 0) {
            float m = acc[0];
            #pragma unroll
            for (int e = 1; e < NE; ++e) m = fmaxf(m, acc[e]);
            float raw[NE]; float s = 0.f;
            #pragma unroll
            for (int e = 0; e < NE; ++e) { raw[e] = expf(acc[e] - m); s += raw[e]; }
            #pragma unroll
            for (int e = 0; e < NE; ++e) raw[e] = raw[e] / s;
            int i1 = 0; float g1 = raw[0];
            #pragma unroll
            for (int e = 1; e < NE; ++e) if (raw[e] > g1) { g1 = raw[e]; i1 = e; }
            int i2 = -1; float g2 = -1.f;
            #pragma unroll
            for (int e = 0; e < NE; ++e) if (e != i1 && raw[e] > g2) { g2 = raw[e]; i2 = e; }
            float denom = g1 + g2 + 1e-9f;
            float g1n = g1 / denom, g2n = g2 / denom;
            bool flag = probs[tok] < (g2n / 0.2f);
            idx1a[tok] = i1;
            idx2a[tok] = flag ? i2 : -1;
            g1a[tok] = g1n;
            g2a[tok] = g2n;
            pos1a[tok] = -1;
            pos2a[tok] = -1;
        }
    }
}

// ---------------- scan: one wave per (b,e), ballot prefix cumsum ----------------
__global__ __launch_bounds__(64) void scan_kernel(const int* __restrict__ idx1a,
                                                  const int* __restrict__ idx2a,
                                                  int* __restrict__ pos1a, int* __restrict__ pos2a,
                                                  int* __restrict__ slot_token) {
    const int bb = blockIdx.x;              // 64
    const int b = bb >> 4, e = bb & 15;
    const int l = threadIdx.x;
    int* slot = slot_token + (e * NB + b) * CAP;
    const unsigned long long below = (l == 0) ? 0ull : ((1ull << l) - 1ull);
    int c = 0;
    for (int base = 0; base < NN; base += 64) {
        int n = base + l;
        bool p = (idx1a[b * NN + n] == e);
        unsigned long long m = __ballot(p);
        int pre = __popcll(m & below);
        if (p) {
            int pos = c + pre;
            if (pos < CAP) { slot[pos] = n; pos1a[b * NN + n] = pos; }
        }
        c += __popcll(m);
    }
    int c2 = (c < CAP) ? c : CAP;
    for (int base = 0; base < NN; base += 64) {
        int n = base + l;
        bool p = (idx2a[b * NN + n] == e);
        unsigned long long m = __ballot(p);
        int pre = __popcll(m & below);
        if (p) {
            int pos = c2 + pre;
            if (pos < CAP) { slot[pos] = n; pos2a[b * NN + n] = pos; }
        }
        c2 += __popcll(m);
    }
    int nfill = (c2 < CAP) ? c2 : CAP;
    for (int i = nfill + l; i < CAP; i += 64) slot[i] = -1;
}

// ---------------- expert MFMA: s[slot] = sum_h lrelu( (h @ We1[e])[slot][h] ) * u[e][h] ----------------
__global__ __launch_bounds__(512) void expert_mfma_kernel(const unsigned short* __restrict__ hbf,
                                                          const unsigned short* __restrict__ We1T,
                                                          const float* __restrict__ u,
                                                          const int* __restrict__ slot_token,
                                                          const float* __restrict__ zbuf,
                                                          float* __restrict__ s_slot) {
    __shared__ char Ash[65536];             // 64 slots x 512 k bf16, swizzled rows of 1024B
    __shared__ char Bsh[2][32768];          // 256 h x 64 k bf16, swizzled rows of 128B
    __shared__ float u_lds[NH];
    __shared__ float sbuf[8][32];
    __shared__ int toks[64];
    const int tid = threadIdx.x;
    const int w = tid >> 6, l = tid & 63;
    const int wm = w >> 2, wn = w & 3;      // 2 x 4 wave grid, wave tile 32x64
    const int lr = l & 15, lk = l >> 4;
    const int e = blockIdx.y, chunk = blockIdx.x;
    const int b = chunk >> 2, c0 = (chunk & 3) * 64;

    if (tid < 64) toks[tid] = slot_token[(e * NB + b) * CAP + c0 + tid];
    u_lds[tid] = u[e * NH + tid];
    u_lds[tid + 512] = u[e * NH + tid + 512];
    __syncthreads();
    // stage A: gather 64 token rows (full K) into LDS, swizzled source (rule #21)
    #pragma unroll
    for (int i = 0; i < 8; ++i) {
        int r = i * 8 + w;                  // wave-uniform row
        int t = toks[r];
        int sb = (l * 16) ^ ((r & 7) << 4);
        const char* src = (t >= 0) ? ((const char*)hbf + ((size_t)(b * NN + t) * ND) * 2 + sb)
                                   : ((const char*)zbuf + sb);
        gload16(src, Ash + i * 8192 + w * 1024);
    }
    auto stageB = [&](int s, int buf) {
        int Hc = s >> 3, Ks = s & 7;
        #pragma unroll
        for (int i = 0; i < 4; ++i) {
            int o = i * 8192 + tid * 16;
            int r = o >> 7, bb = o & 127;
            int sb = bb ^ ((r & 7) << 4);
            gload16((const char*)We1T + ((size_t)(e * NH + Hc * 256 + r) * ND + Ks * 64) * 2 + sb,
                    Bsh[buf] + i * 8192 + w * 1024);
        }
    };
    f32x4 acc[2][4] = {};
    float srow[2][4] = {};
    stageB(0, 0);
    __syncthreads();
    for (int s = 0; s < 32; ++s) {          // 4 H-chunks x 8 K-stages
        int buf = s & 1;
        if (s < 31) stageB(s + 1, buf ^ 1);
        #pragma unroll
        for (int k32 = 0; k32 < 2; ++k32) {
            int kbA = ((s & 7) * 64 + k32 * 32 + 8 * lk) * 2;
            int kbB = (k32 * 32 + 8 * lk) * 2;
            bf16x8 a[2], bfr[4];
            #pragma unroll
            for (int mi = 0; mi < 2; ++mi) {
                int row = wm * 32 + mi * 16 + lr;
                a[mi] = *(const bf16x8*)(Ash + row * 1024 + (kbA ^ ((row & 7) << 4)));
            }
            #pragma unroll
            for (int ni = 0; ni < 4; ++ni) {
                int row = wn * 64 + ni * 16 + lr;
                bfr[ni] = *(const bf16x8*)(Bsh[buf] + row * 128 + (kbB ^ ((row & 7) << 4)));
            }
            #pragma unroll
            for (int mi = 0; mi < 2; ++mi)
                #pragma unroll
                for (int ni = 0; ni < 4; ++ni)
                    acc[mi][ni] = __builtin_amdgcn_mfma_f32_16x16x32_bf16(a[mi], bfr[ni], acc[mi][ni], 0, 0, 0);
        }
        if ((s & 7) == 7) {                 // H-chunk done: fuse lrelu . u, reset acc
            int Hc = s >> 3;
            #pragma unroll
            for (int mi = 0; mi < 2; ++mi)
                #pragma unroll
                for (int ni = 0; ni < 4; ++ni) {
                    float uu = u_lds[Hc * 256 + wn * 64 + ni * 16 + lr];
                    #pragma unroll
                    for (int r = 0; r < 4; ++r) {
                        float x = acc[mi][ni][r];
                        x = (x > 0.f) ? x : 0.01f * x;
                        srow[mi][r] = fmaf(x, uu, srow[mi][r]);
                        acc[mi][ni][r] = 0.f;
                    }
                }
        }
        __syncthreads();
    }
    // reduce over the 16 col-lanes, then across the 4 N-waves via LDS
    #pragma unroll
    for (int off = 1; off < 16; off <<= 1)
        #pragma unroll
        for (int mi = 0; mi < 2; ++mi)
            #pragma unroll
            for (int r = 0; r < 4; ++r)
                srow[mi][r] += __shfl_xor(srow[mi][r], off);
    if (lr == 0) {
        #pragma unroll
        for (int mi = 0; mi < 2; ++mi)
            #pragma unroll
            for (int r = 0; r < 4; ++r)
                sbuf[w][mi * 16 + lk * 4 + r] = srow[mi][r];
    }
    __syncthreads();
    if (tid < 64) {
        int q = tid >> 5, rl = tid & 31;
        float s = sbuf[q * 4 + 0][rl] + sbuf[q * 4 + 1][rl] + sbuf[q * 4 + 2][rl] + sbuf[q * 4 + 3][rl];
        s_slot[(e * NB + b) * CAP + c0 + tid] = s;
    }
}

// ---------------- final combine + collapsed output projection ----------------
__global__ __launch_bounds__(256) void final_kernel(const int* __restrict__ idx1a, const int* __restrict__ idx2a,
                                                    const int* __restrict__ pos1a, const int* __restrict__ pos2a,
                                                    const float* __restrict__ g1a, const float* __restrict__ g2a,
                                                    const float* __restrict__ s_slot, const float* __restrict__ c0,
                                                    float* __restrict__ out) {
    int tok = blockIdx.x * 256 + threadIdx.x;
    int b = tok >> 11;
    float s = *c0;
    int p1 = pos1a[tok];
    if (p1 >= 0) s += g1a[tok] * s_slot[(idx1a[tok] * NB + b) * CAP + p1];
    int p2 = pos2a[tok];
    if (p2 >= 0) s += g2a[tok] * s_slot[(idx2a[tok] * NB + b) * CAP + p2];
    out[tok] = s;
}

extern "C" void kernel_launch(void* const* d_in, const int* in_sizes, int n_in,
                              void* d_out, int out_size, void* d_ws, size_t ws_size,
                              hipStream_t stream) {
    const float* X    = (const float*)d_in[0];
    const float* probs= (const float*)d_in[1];
    const float* W1   = (const float*)d_in[2];
    const float* b1   = (const float*)d_in[3];
    const float* Wg   = (const float*)d_in[4];
    const float* We1  = (const float*)d_in[5];
    const float* We2  = (const float*)d_in[6];
    const float* W3   = (const float*)d_in[7];
    const float* b3   = (const float*)d_in[8];
    const float* W4   = (const float*)d_in[9];
    const float* b4   = (const float*)d_in[10];
    float* out = (float*)d_out;

    char* ws = (char*)d_ws;
    size_t off = 0;
    auto alloc = [&](size_t bytes) { void* p = ws + off; off += (bytes + 255) & ~(size_t)255; return p; };
    unsigned short* Xbf  = (unsigned short*)alloc((size_t)NTOK * ND * 2);     // 8 MB
    unsigned short* hbf  = (unsigned short*)alloc((size_t)NTOK * ND * 2);     // 8 MB
    unsigned short* W1T  = (unsigned short*)alloc((size_t)ND * ND * 2);       // 512 KB
    unsigned short* We1T = (unsigned short*)alloc((size_t)NE * NH * ND * 2);  // 16 MB
    float* WcT     = (float*)alloc(NE * ND * 4);
    float* vv      = (float*)alloc(ND * 4);
    float* c0      = (float*)alloc(256);
    float* u       = (float*)alloc(NE * NH * 4);
    float* zbuf    = (float*)alloc(1024);
    int*   idx1a   = (int*)alloc(NTOK * 4);
    int*   idx2a   = (int*)alloc(NTOK * 4);
    int*   pos1a   = (int*)alloc(NTOK * 4);
    int*   pos2a   = (int*)alloc(NTOK * 4);
    float* g1a     = (float*)alloc(NTOK * 4);
    float* g2a     = (float*)alloc(NTOK * 4);
    int*   slot_tok= (int*)alloc(NE * NB * CAP * 4);
    float* s_slot  = (float*)alloc(NE * NB * CAP * 4);
    (void)ws_size; (void)in_sizes; (void)n_in; (void)out_size;

    convert_x_kernel<<<NTOK * ND / 1024, 256, 0, stream>>>(X, Xbf, zbuf);
    transpose_bf16_kernel<<<dim3(ND / 32, ND / 32, 1), 256, 0, stream>>>(W1, W1T, ND, ND);
    transpose_bf16_kernel<<<dim3(NH / 32, ND / 32, NE), 256, 0, stream>>>(We1, We1T, ND, NH);
    wc_kernel<<<ND / 16, 256, 0, stream>>>(W1, Wg, WcT);
    v_kernel<<<2, 256, 0, stream>>>(W3, b3, W4, b4, vv, c0);
    u_kernel<<<NE * (NH / 16), 256, 0, stream>>>(We2, vv, u);
    linear1_mfma_kernel<<<dim3(ND / 128, NTOK / 128), 512, 0, stream>>>(Xbf, W1T, b1, hbf);
    gating_kernel<<<NTOK / 16, 256, 0, stream>>>(X, WcT, probs, idx1a, idx2a, g1a, g2a, pos1a, pos2a);
    scan_kernel<<<NB * NE, 64, 0, stream>>>(idx1a, idx2a, pos1a, pos2a, slot_tok);
    expert_mfma_kernel<<<dim3(16, NE), 512, 0, stream>>>(hbf, We1T, u, slot_tok, zbuf, s_slot);
    final_kernel<<<NTOK / 256, 256, 0, stream>>>(idx1a, idx2a, pos1a, pos2a, g1a, g2a, s_slot, c0, out);
}

// Round 3
// 128.075 us; speedup vs baseline: 3.3372x; 1.0847x over previous
//
#include <hip/hip_runtime.h>
#include <hip/hip_bf16.h>

#define NB 4
#define NN 2048
#define ND 512
#define NE 16
#define NH 1024
#define CAP 256
#define NTOK (NB*NN)

typedef __attribute__((ext_vector_type(8))) short bf16x8;
typedef __attribute__((ext_vector_type(4))) float f32x4;

__device__ __forceinline__ void gload16(const void* gsrc, void* lds) {
    __builtin_amdgcn_global_load_lds((const __attribute__((address_space(1))) void*)gsrc,
                                     (__attribute__((address_space(3))) void*)lds, 16, 0, 0);
}
__device__ __forceinline__ unsigned short f2bf(float f) {
    union { __hip_bfloat16 b; unsigned short u; } v; v.b = __float2bfloat16(f); return v.u;
}

// ---------------- fused prep: convert X, transpose W1/We1 -> bf16, Wc, u ----------------
// block ranges: [0,4096) convert X ; [4096,4352) W1^T ; [4352,12544) We1^T ;
//               [12544,12576) WcT ; [12576,13600) u (inlines v = W3@W4)
__global__ __launch_bounds__(256) void prep_kernel(const float* __restrict__ X,
                                                   const float* __restrict__ W1,
                                                   const float* __restrict__ Wg,
                                                   const float* __restrict__ We1,
                                                   const float* __restrict__ We2,
                                                   const float* __restrict__ W3,
                                                   const float* __restrict__ W4,
                                                   unsigned short* __restrict__ Xbf,
                                                   unsigned short* __restrict__ W1T,
                                                   unsigned short* __restrict__ We1T,
                                                   float* __restrict__ WcT,
                                                   float* __restrict__ u,
                                                   float* __restrict__ zbuf) {
    const int tid = threadIdx.x;
    int bid = blockIdx.x;
    if (bid < 4096) {                                   // ---- convert X -> bf16
        int i = (bid * 256 + tid) * 4;
        float4 v = *(const float4*)(X + i);
        ushort4 o; o.x = f2bf(v.x); o.y = f2bf(v.y); o.z = f2bf(v.z); o.w = f2bf(v.w);
        *(ushort4*)(Xbf + i) = o;
        if (bid == 0) zbuf[tid] = 0.f;
        return;
    }
    bid -= 4096;
    if (bid < 256 + 8192) {                             // ---- transposes f32[R][C] -> bf16[C][R]
        const float* src; unsigned short* dst; int C; size_t zoff; int bx, by;
        const int R = ND;
        if (bid < 256) { src = W1; dst = W1T; C = ND; zoff = 0; bx = bid & 15; by = bid >> 4; }
        else {
            int tb = bid - 256;
            int z = tb >> 9, rem = tb & 511;
            src = We1; dst = We1T; C = NH;
            zoff = (size_t)z * ND * NH; bx = rem & 31; by = rem >> 5;
        }
        __shared__ float t[32][33];
        int r0 = by * 32, c0 = bx * 32;
        #pragma unroll
        for (int i = 0; i < 4; ++i) {
            int idx = tid + 256 * i;
            int lr = idx >> 5, lc = idx & 31;
            t[lr][lc] = src[zoff + (size_t)(r0 + lr) * C + (c0 + lc)];
        }
        __syncthreads();
        #pragma unroll
        for (int i = 0; i < 4; ++i) {
            int idx = tid + 256 * i;
            int lr = idx >> 5, lc = idx & 31;
            dst[zoff + (size_t)(c0 + lr) * R + (r0 + lc)] = f2bf(t[lc][lr]);
        }
        return;
    }
    bid -= 8448;
    if (bid < 32) {                                     // ---- WcT[e][d] = (W1 @ Wg)^T
        int d = bid * 16 + (tid >> 4);
        int e = tid & 15;
        float s = 0.f;
        for (int j = 0; j < ND; ++j) s = fmaf(W1[d * ND + j], Wg[j * NE + e], s);
        WcT[e * ND + d] = s;
        return;
    }
    bid -= 32;
    {                                                   // ---- u[e][h] = We2[e][h][:] . (W3@W4)
        __shared__ float vvs[ND];
        int d0 = tid * 2;
        #pragma unroll
        for (int q = 0; q < 2; ++q) {
            int d = d0 + q;
            float s = 0.f;
            #pragma unroll
            for (int j = 0; j < 4; ++j) s += W3[d * 4 + j] * W4[j];
            vvs[d] = s;
        }
        __syncthreads();
        const int e = bid >> 6, rb = bid & 63;
        const int rl = tid >> 4, dl = tid & 15;
        const int hrow = rb * 16 + rl;
        const float* wrow = We2 + ((size_t)e * NH + hrow) * ND;
        float sum = 0.f;
        for (int j = 0; j < 32; ++j) sum += wrow[dl + 16 * j] * vvs[dl + 16 * j];
        #pragma unroll
        for (int off = 8; off >= 1; off >>= 1) sum += __shfl_down(sum, off, 16);
        if (dl == 0) u[e * NH + hrow] = sum;
    }
}

// ---------------- linear1 MFMA: hbf = bf16( Xbf @ W1 + b1 ) ----------------
__global__ __launch_bounds__(512) void linear1_mfma_kernel(const unsigned short* __restrict__ Xbf,
                                                           const unsigned short* __restrict__ W1T,
                                                           const float* __restrict__ b1,
                                                           unsigned short* __restrict__ hbf) {
    __shared__ char Ash[2][16384];
    __shared__ char Bsh[2][16384];
    const int tid = threadIdx.x;
    const int w = tid >> 6, l = tid & 63;
    const int wm = w >> 1, wn = w & 1;      // 4 x 2 wave grid, wave tile 32x64
    const int lr = l & 15, lk = l >> 4;
    const int m0 = blockIdx.y * 128, n0 = blockIdx.x * 128;

    auto stage = [&](int Ks, int buf) {
        #pragma unroll
        for (int i = 0; i < 2; ++i) {
            int o = i * 8192 + tid * 16;
            int r = o >> 7, bb = o & 127;
            int sb = bb ^ ((r & 7) << 4);
            gload16((const char*)Xbf + ((size_t)(m0 + r) * ND + Ks * 64) * 2 + sb,
                    Ash[buf] + i * 8192 + w * 1024);
            gload16((const char*)W1T + ((size_t)(n0 + r) * ND + Ks * 64) * 2 + sb,
                    Bsh[buf] + i * 8192 + w * 1024);
        }
    };

    f32x4 acc[2][4] = {};
    stage(0, 0);
    __syncthreads();
    for (int Ks = 0; Ks < 8; ++Ks) {
        int buf = Ks & 1;
        if (Ks < 7) stage(Ks + 1, buf ^ 1);
        #pragma unroll
        for (int k32 = 0; k32 < 2; ++k32) {
            int kb = (k32 * 32 + 8 * lk) * 2;
            bf16x8 a[2], bfr[4];
            #pragma unroll
            for (int mi = 0; mi < 2; ++mi) {
                int row = wm * 32 + mi * 16 + lr;
                a[mi] = *(const bf16x8*)(Ash[buf] + row * 128 + (kb ^ ((row & 7) << 4)));
            }
            #pragma unroll
            for (int ni = 0; ni < 4; ++ni) {
                int row = wn * 64 + ni * 16 + lr;
                bfr[ni] = *(const bf16x8*)(Bsh[buf] + row * 128 + (kb ^ ((row & 7) << 4)));
            }
            #pragma unroll
            for (int mi = 0; mi < 2; ++mi)
                #pragma unroll
                for (int ni = 0; ni < 4; ++ni)
                    acc[mi][ni] = __builtin_amdgcn_mfma_f32_16x16x32_bf16(a[mi], bfr[ni], acc[mi][ni], 0, 0, 0);
        }
        __syncthreads();
    }
    #pragma unroll
    for (int mi = 0; mi < 2; ++mi)
        #pragma unroll
        for (int ni = 0; ni < 4; ++ni) {
            int col = n0 + wn * 64 + ni * 16 + lr;
            float bb1 = b1[col];
            #pragma unroll
            for (int r = 0; r < 4; ++r) {
                int m = m0 + wm * 32 + mi * 16 + lk * 4 + r;
                hbf[(size_t)m * ND + col] = f2bf(acc[mi][ni][r] + bb1);
            }
        }
}

// ---------------- gating from X and WcT (f32, matches reference numerics) ----------------
__global__ __launch_bounds__(256) void gating_kernel(const float* __restrict__ X,
                                                     const float* __restrict__ WcT,
                                                     const float* __restrict__ probs,
                                                     int* __restrict__ idx1a, int* __restrict__ idx2a,
                                                     float* __restrict__ g1a, float* __restrict__ g2a,
                                                     int* __restrict__ pos1a, int* __restrict__ pos2a) {
    __shared__ float wc[NE * ND];           // 32KB
    const int tid = threadIdx.x;
    #pragma unroll
    for (int i = 0; i < 32; ++i) wc[tid + 256 * i] = WcT[tid + 256 * i];
    __syncthreads();
    const int w = tid >> 6, l = tid & 63;
    for (int j = 0; j < 4; ++j) {
        int tok = blockIdx.x * 16 + 4 * j + w;
        const float* xrow = X + (size_t)tok * ND;
        float acc[NE] = {};
        for (int jj = 0; jj < 8; ++jj) {
            float xv = xrow[64 * jj + l];
            #pragma unroll
            for (int e = 0; e < NE; ++e) acc[e] = fmaf(xv, wc[e * ND + 64 * jj + l], acc[e]);
        }
        #pragma unroll
        for (int off = 32; off >= 1; off >>= 1)
            #pragma unroll
            for (int e = 0; e < NE; ++e) acc[e] += __shfl_xor(acc[e], off);

        if (l == 0) {
            float m = acc[0];
            #pragma unroll
            for (int e = 1; e < NE; ++e) m = fmaxf(m, acc[e]);
            float raw[NE]; float s = 0.f;
            #pragma unroll
            for (int e = 0; e < NE; ++e) { raw[e] = expf(acc[e] - m); s += raw[e]; }
            #pragma unroll
            for (int e = 0; e < NE; ++e) raw[e] = raw[e] / s;
            int i1 = 0; float g1 = raw[0];
            #pragma unroll
            for (int e = 1; e < NE; ++e) if (raw[e] > g1) { g1 = raw[e]; i1 = e; }
            int i2 = -1; float g2 = -1.f;
            #pragma unroll
            for (int e = 0; e < NE; ++e) if (e != i1 && raw[e] > g2) { g2 = raw[e]; i2 = e; }
            float denom = g1 + g2 + 1e-9f;
            float g1n = g1 / denom, g2n = g2 / denom;
            bool flag = probs[tok] < (g2n / 0.2f);
            idx1a[tok] = i1;
            idx2a[tok] = flag ? i2 : -1;
            g1a[tok] = g1n;
            g2a[tok] = g2n;
            pos1a[tok] = -1;
            pos2a[tok] = -1;
        }
    }
}

// ---------------- scan: one wave per (b,e), ballot prefix cumsum ----------------
__global__ __launch_bounds__(64) void scan_kernel(const int* __restrict__ idx1a,
                                                  const int* __restrict__ idx2a,
                                                  int* __restrict__ pos1a, int* __restrict__ pos2a,
                                                  int* __restrict__ slot_token) {
    const int bb = blockIdx.x;              // 64
    const int b = bb >> 4, e = bb & 15;
    const int l = threadIdx.x;
    int* slot = slot_token + (e * NB + b) * CAP;
    const unsigned long long below = (l == 0) ? 0ull : ((1ull << l) - 1ull);
    int c = 0;
    for (int base = 0; base < NN; base += 64) {
        int n = base + l;
        bool p = (idx1a[b * NN + n] == e);
        unsigned long long m = __ballot(p);
        int pre = __popcll(m & below);
        if (p) {
            int pos = c + pre;
            if (pos < CAP) { slot[pos] = n; pos1a[b * NN + n] = pos; }
        }
        c += __popcll(m);
    }
    int c2 = (c < CAP) ? c : CAP;
    for (int base = 0; base < NN; base += 64) {
        int n = base + l;
        bool p = (idx2a[b * NN + n] == e);
        unsigned long long m = __ballot(p);
        int pre = __popcll(m & below);
        if (p) {
            int pos = c2 + pre;
            if (pos < CAP) { slot[pos] = n; pos2a[b * NN + n] = pos; }
        }
        c2 += __popcll(m);
    }
    int nfill = (c2 < CAP) ? c2 : CAP;
    for (int i = nfill + l; i < CAP; i += 64) slot[i] = -1;
}

// ---------------- expert MFMA with expert->XCD swizzle ----------------
__global__ __launch_bounds__(512) void expert_mfma_kernel(const unsigned short* __restrict__ hbf,
                                                          const unsigned short* __restrict__ We1T,
                                                          const float* __restrict__ u,
                                                          const int* __restrict__ slot_token,
                                                          const float* __restrict__ zbuf,
                                                          float* __restrict__ s_slot) {
    __shared__ char Ash[65536];             // 64 slots x 512 k bf16, swizzled rows of 1024B
    __shared__ char Bsh[2][32768];          // 256 h x 64 k bf16, swizzled rows of 128B
    __shared__ float u_lds[NH];
    __shared__ float sbuf[8][32];
    __shared__ int toks[64];
    const int tid = threadIdx.x;
    const int w = tid >> 6, l = tid & 63;
    const int wm = w >> 2, wn = w & 3;      // 2 x 4 wave grid, wave tile 32x64
    const int lr = l & 15, lk = l >> 4;
    // XCD swizzle: all 16 blocks of an expert share an XCD (bid % 8 == e % 8)
    const int bid = blockIdx.x;
    const int e = (bid & 7) | ((bid >> 7) << 3);
    const int chunk = (bid >> 3) & 15;
    const int b = chunk >> 2, c0 = (chunk & 3) * 64;

    if (tid < 64) toks[tid] = slot_token[(e * NB + b) * CAP + c0 + tid];
    u_lds[tid] = u[e * NH + tid];
    u_lds[tid + 512] = u[e * NH + tid + 512];
    __syncthreads();
    // stage A: gather 64 token rows (full K) into LDS, swizzled source (rule #21)
    #pragma unroll
    for (int i = 0; i < 8; ++i) {
        int r = i * 8 + w;                  // wave-uniform row
        int t = toks[r];
        int sb = (l * 16) ^ ((r & 7) << 4);
        const char* src = (t >= 0) ? ((const char*)hbf + ((size_t)(b * NN + t) * ND) * 2 + sb)
                                   : ((const char*)zbuf + sb);
        gload16(src, Ash + i * 8192 + w * 1024);
    }
    auto stageB = [&](int s, int buf) {
        int Hc = s >> 3, Ks = s & 7;
        #pragma unroll
        for (int i = 0; i < 4; ++i) {
            int o = i * 8192 + tid * 16;
            int r = o >> 7, bb = o & 127;
            int sb = bb ^ ((r & 7) << 4);
            gload16((const char*)We1T + ((size_t)(e * NH + Hc * 256 + r) * ND + Ks * 64) * 2 + sb,
                    Bsh[buf] + i * 8192 + w * 1024);
        }
    };
    f32x4 acc[2][4] = {};
    float srow[2][4] = {};
    stageB(0, 0);
    __syncthreads();
    for (int s = 0; s < 32; ++s) {          // 4 H-chunks x 8 K-stages
        int buf = s & 1;
        if (s < 31) stageB(s + 1, buf ^ 1);
        #pragma unroll
        for (int k32 = 0; k32 < 2; ++k32) {
            int kbA = ((s & 7) * 64 + k32 * 32 + 8 * lk) * 2;
            int kbB = (k32 * 32 + 8 * lk) * 2;
            bf16x8 a[2], bfr[4];
            #pragma unroll
            for (int mi = 0; mi < 2; ++mi) {
                int row = wm * 32 + mi * 16 + lr;
                a[mi] = *(const bf16x8*)(Ash + row * 1024 + (kbA ^ ((row & 7) << 4)));
            }
            #pragma unroll
            for (int ni = 0; ni < 4; ++ni) {
                int row = wn * 64 + ni * 16 + lr;
                bfr[ni] = *(const bf16x8*)(Bsh[buf] + row * 128 + (kbB ^ ((row & 7) << 4)));
            }
            #pragma unroll
            for (int mi = 0; mi < 2; ++mi)
                #pragma unroll
                for (int ni = 0; ni < 4; ++ni)
                    acc[mi][ni] = __builtin_amdgcn_mfma_f32_16x16x32_bf16(a[mi], bfr[ni], acc[mi][ni], 0, 0, 0);
        }
        if ((s & 7) == 7) {                 // H-chunk done: fuse lrelu . u, reset acc
            int Hc = s >> 3;
            #pragma unroll
            for (int mi = 0; mi < 2; ++mi)
                #pragma unroll
                for (int ni = 0; ni < 4; ++ni) {
                    float uu = u_lds[Hc * 256 + wn * 64 + ni * 16 + lr];
                    #pragma unroll
                    for (int r = 0; r < 4; ++r) {
                        float x = acc[mi][ni][r];
                        x = (x > 0.f) ? x : 0.01f * x;
                        srow[mi][r] = fmaf(x, uu, srow[mi][r]);
                        acc[mi][ni][r] = 0.f;
                    }
                }
        }
        __syncthreads();
    }
    // reduce over the 16 col-lanes, then across the 4 N-waves via LDS
    #pragma unroll
    for (int off = 1; off < 16; off <<= 1)
        #pragma unroll
        for (int mi = 0; mi < 2; ++mi)
            #pragma unroll
            for (int r = 0; r < 4; ++r)
                srow[mi][r] += __shfl_xor(srow[mi][r], off);
    if (lr == 0) {
        #pragma unroll
        for (int mi = 0; mi < 2; ++mi)
            #pragma unroll
            for (int r = 0; r < 4; ++r)
                sbuf[w][mi * 16 + lk * 4 + r] = srow[mi][r];
    }
    __syncthreads();
    if (tid < 64) {
        int q = tid >> 5, rl = tid & 31;
        float s = sbuf[q * 4 + 0][rl] + sbuf[q * 4 + 1][rl] + sbuf[q * 4 + 2][rl] + sbuf[q * 4 + 3][rl];
        s_slot[(e * NB + b) * CAP + c0 + tid] = s;
    }
}

// ---------------- final combine + collapsed output projection ----------------
__global__ __launch_bounds__(256) void final_kernel(const int* __restrict__ idx1a, const int* __restrict__ idx2a,
                                                    const int* __restrict__ pos1a, const int* __restrict__ pos2a,
                                                    const float* __restrict__ g1a, const float* __restrict__ g2a,
                                                    const float* __restrict__ s_slot,
                                                    const float* __restrict__ b3, const float* __restrict__ W4,
                                                    const float* __restrict__ b4,
                                                    float* __restrict__ out) {
    int tok = blockIdx.x * 256 + threadIdx.x;
    int b = tok >> 11;
    float c0v = 0.f;
    #pragma unroll
    for (int j = 0; j < 4; ++j) c0v += b3[j] * W4[j];
    float s = c0v + b4[0];
    int p1 = pos1a[tok];
    if (p1 >= 0) s += g1a[tok] * s_slot[(idx1a[tok] * NB + b) * CAP + p1];
    int p2 = pos2a[tok];
    if (p2 >= 0) s += g2a[tok] * s_slot[(idx2a[tok] * NB + b) * CAP + p2];
    out[tok] = s;
}

extern "C" void kernel_launch(void* const* d_in, const int* in_sizes, int n_in,
                              void* d_out, int out_size, void* d_ws, size_t ws_size,
                              hipStream_t stream) {
    const float* X    = (const float*)d_in[0];
    const float* probs= (const float*)d_in[1];
    const float* W1   = (const float*)d_in[2];
    const float* b1   = (const float*)d_in[3];
    const float* Wg   = (const float*)d_in[4];
    const float* We1  = (const float*)d_in[5];
    const float* We2  = (const float*)d_in[6];
    const float* W3   = (const float*)d_in[7];
    const float* b3   = (const float*)d_in[8];
    const float* W4   = (const float*)d_in[9];
    const float* b4   = (const float*)d_in[10];
    float* out = (float*)d_out;

    char* ws = (char*)d_ws;
    size_t off = 0;
    auto alloc = [&](size_t bytes) { void* p = ws + off; off += (bytes + 255) & ~(size_t)255; return p; };
    unsigned short* Xbf  = (unsigned short*)alloc((size_t)NTOK * ND * 2);     // 8 MB
    unsigned short* hbf  = (unsigned short*)alloc((size_t)NTOK * ND * 2);     // 8 MB
    unsigned short* W1T  = (unsigned short*)alloc((size_t)ND * ND * 2);       // 512 KB
    unsigned short* We1T = (unsigned short*)alloc((size_t)NE * NH * ND * 2);  // 16 MB
    float* WcT     = (float*)alloc(NE * ND * 4);
    float* u       = (float*)alloc(NE * NH * 4);
    float* zbuf    = (float*)alloc(1024);
    int*   idx1a   = (int*)alloc(NTOK * 4);
    int*   idx2a   = (int*)alloc(NTOK * 4);
    int*   pos1a   = (int*)alloc(NTOK * 4);
    int*   pos2a   = (int*)alloc(NTOK * 4);
    float* g1a     = (float*)alloc(NTOK * 4);
    float* g2a     = (float*)alloc(NTOK * 4);
    int*   slot_tok= (int*)alloc(NE * NB * CAP * 4);
    float* s_slot  = (float*)alloc(NE * NB * CAP * 4);
    (void)ws_size; (void)in_sizes; (void)n_in; (void)out_size;

    prep_kernel<<<13600, 256, 0, stream>>>(X, W1, Wg, We1, We2, W3, W4,
                                           Xbf, W1T, We1T, WcT, u, zbuf);
    linear1_mfma_kernel<<<dim3(ND / 128, NTOK / 128), 512, 0, stream>>>(Xbf, W1T, b1, hbf);
    gating_kernel<<<NTOK / 16, 256, 0, stream>>>(X, WcT, probs, idx1a, idx2a, g1a, g2a, pos1a, pos2a);
    scan_kernel<<<NB * NE, 64, 0, stream>>>(idx1a, idx2a, pos1a, pos2a, slot_tok);
    expert_mfma_kernel<<<256, 512, 0, stream>>>(hbf, We1T, u, slot_tok, zbuf, s_slot);
    final_kernel<<<NTOK / 256, 256, 0, stream>>>(idx1a, idx2a, pos1a, pos2a, g1a, g2a, s_slot, b3, W4, b4, out);
}